// Round 7
// baseline (219.954 us; speedup 1.0000x reference)
//
#include <hip/hip_runtime.h>
#include <hip/hip_bf16.h>

typedef __bf16 bf16x8 __attribute__((ext_vector_type(8)));
typedef float f32x16 __attribute__((ext_vector_type(16)));
typedef unsigned short ushort_t;

#define NSENT 8192
#define LSEQ  120
#define GBAGS 256
#define WDIM_ 50
#define DFILT 230
#define NCLS  53
#define KSTEPS 12
#define BFRAG_ELEMS (24*256*8)
#define LROWS 130
#define SPB 8                      // sentences per block (8 waves, 512 threads)
#define SENT_BYTES (LSEQ * 128)    // 15360 B materialized image per sentence

// workspace byte offsets
#define OFF_BFRAG 0
#define OFF_WV64  196608
#define OFF_PF1B  (OFF_WV64 + 10240000)
#define OFF_PF2B  (OFF_PF1B + 2048)
#define OFF_SENT  (OFF_PF2B + 2048)
#define OFF_EMB   (OFF_SENT + 7536640)   // emb image buffer (per-pass)

static __device__ __forceinline__ ushort_t f2bf(float f) {
    unsigned int u = __float_as_uint(f);
    unsigned int lsb = (u >> 16) & 1u;
    u += 0x7fffu + lsb;
    return (ushort_t)(u >> 16);
}

// async global->LDS, 16B per lane; per-lane GLOBAL address, linear LDS dest
static __device__ __forceinline__ void gll16(const void* g, void* l) {
    __builtin_amdgcn_global_load_lds(
        (const __attribute__((address_space(1))) unsigned int*)g,
        (__attribute__((address_space(3))) unsigned int*)l, 16, 0, 0);
}

// ---------------- prep 0: Wc -> MFMA B-fragment layout; pf1/pf2 -> bf16 ----------------
__global__ __launch_bounds__(256) void pcnn_prep_b(const float* __restrict__ Wc,
                                                   const float* __restrict__ pf1,
                                                   const float* __restrict__ pf2,
                                                   ushort_t* __restrict__ Bfrag,
                                                   ushort_t* __restrict__ pf1b,
                                                   ushort_t* __restrict__ pf2b) {
    int idx = blockIdx.x * 256 + threadIdx.x;
    if (idx < 1010) pf1b[idx] = f2bf(pf1[idx]);
    else if (idx < 2020) pf2b[idx - 1010] = f2bf(pf2[idx - 1010]);
    if (idx >= BFRAG_ELEMS) return;
    int c   = idx >> 11;
    int rem = idx & 2047;
    int d   = rem >> 3;
    int j   = rem & 7;
    int k   = c * 8 + j;
    int dh  = k >> 6;
    int w   = k & 63;
    float val = (d < DFILT && w < 60) ? Wc[(d * 3 + dh) * 60 + w] : 0.0f;
    Bfrag[idx] = f2bf(val);
}

// ---------------- prep 1: Wv (80000x50 fp32) -> Wv64 (80000x64 bf16, zero-padded) --------
__global__ __launch_bounds__(256) void pcnn_prep_wv(const float* __restrict__ Wv,
                                                    ushort_t* __restrict__ Wv64) {
    int idx = blockIdx.x * 256 + threadIdx.x;   // 5,120,000 total
    int r = idx >> 6, k = idx & 63;
    float val = (k < WDIM_) ? Wv[r * WDIM_ + k] : 0.0f;
    Wv64[idx] = f2bf(val);
}

// ---------------- gather: materialize swizzled LDS-image rows, one thread per (n,l) ------
// Streaming, no barriers, max TLP: random L3-resident row reads hide under concurrency.
__global__ __launch_bounds__(256) void pcnn_gather(
    const int* __restrict__ x, const int* __restrict__ ld, const int* __restrict__ rd,
    const ushort_t* __restrict__ Wv64, const ushort_t* __restrict__ pf1b,
    const ushort_t* __restrict__ pf2b,
    unsigned char* __restrict__ emb, int row_base, int nrows) {
    int idx = blockIdx.x * 256 + threadIdx.x;     // pass-local row
    if (idx >= nrows) return;
    int g = row_base + idx;                        // global (n,l) row
    int l = idx % LSEQ;                            // row_base is a multiple of LSEQ
    int tok = x[g], lp = ld[g], rp = rd[g];

    const uint4* wrow = reinterpret_cast<const uint4*>(Wv64 + (size_t)tok * 64);
    uint4 c0 = wrow[0], c1 = wrow[1], c2 = wrow[2];
    uint4 c3 = wrow[3], c4 = wrow[4], c5 = wrow[5];
    unsigned int wv4849 = *reinterpret_cast<const unsigned int*>(Wv64 + (size_t)tok * 64 + 48);
    ushort_t p10 = pf1b[lp * 5 + 0], p11 = pf1b[lp * 5 + 1], p12 = pf1b[lp * 5 + 2];
    ushort_t p13 = pf1b[lp * 5 + 3], p14 = pf1b[lp * 5 + 4];
    ushort_t p20 = pf2b[rp * 5 + 0], p21 = pf2b[rp * 5 + 1], p22 = pf2b[rp * 5 + 2];
    ushort_t p23 = pf2b[rp * 5 + 3], p24 = pf2b[rp * 5 + 4];

    uint4 c6, c7;
    c6.x = wv4849;
    c6.y = (unsigned int)p10 | ((unsigned int)p11 << 16);
    c6.z = (unsigned int)p12 | ((unsigned int)p13 << 16);
    c6.w = (unsigned int)p14 | ((unsigned int)p20 << 16);
    c7.x = (unsigned int)p21 | ((unsigned int)p22 << 16);
    c7.y = (unsigned int)p23 | ((unsigned int)p24 << 16);
    c7.z = 0; c7.w = 0;

    unsigned char* base = emb + (size_t)idx * 128;
    int s = (l & 7) << 4;
    *reinterpret_cast<uint4*>(base + ((0 << 4) ^ s)) = c0;
    *reinterpret_cast<uint4*>(base + ((1 << 4) ^ s)) = c1;
    *reinterpret_cast<uint4*>(base + ((2 << 4) ^ s)) = c2;
    *reinterpret_cast<uint4*>(base + ((3 << 4) ^ s)) = c3;
    *reinterpret_cast<uint4*>(base + ((4 << 4) ^ s)) = c4;
    *reinterpret_cast<uint4*>(base + ((5 << 4) ^ s)) = c5;
    *reinterpret_cast<uint4*>(base + ((6 << 4) ^ s)) = c6;
    *reinterpret_cast<uint4*>(base + ((7 << 4) ^ s)) = c7;
}

// ---------------- conv staging: pure sequential global_load_lds from emb image ----------
__device__ __forceinline__ void issue_stage(unsigned char* __restrict__ buf,
                                            const unsigned char* __restrict__ embS, int tid) {
    gll16(embS + tid * 16, buf + tid * 16);
    if (tid < 448)                                  // wave-uniform (wave 7 idles here)
        gll16(embS + (tid + 512) * 16, buf + (tid + 512) * 16);
}

// ---------------- per-wave conv compute: one 32-wide d-tile ----------------
__device__ __forceinline__ void conv_compute(const unsigned char* __restrict__ buf, int n,
    const bf16x8 (&Bf)[KSTEPS], float bcv, float* __restrict__ sent,
    int dcol, int lhalf, int l31) {
    float dmax = -1e30f;
    #pragma unroll
    for (int tt = 0; tt < 4; ++tt) {
        f32x16 acc;
        #pragma unroll
        for (int r = 0; r < 16; ++r) acc[r] = 0.0f;
        int trow = tt * 32 + l31;
        #pragma unroll
        for (int ks = 0; ks < KSTEPS; ++ks) {
            int dh = ks >> 2, q = ks & 3;
            int l = trow + dh;
            int w0 = q * 16 + lhalf * 8;
            int byteoff = l * 128 + ((w0 * 2) ^ ((l & 7) << 4));
            bf16x8 Af = *reinterpret_cast<const bf16x8*>(buf + byteoff);
            acc = __builtin_amdgcn_mfma_f32_32x32x16_bf16(Af, Bf[ks], acc, 0, 0, 0);
        }
        #pragma unroll
        for (int r = 0; r < 16; ++r) {
            int t = tt * 32 + (r & 3) + 8 * (r >> 2) + 4 * lhalf;
            bool valid = (tt < 3) || (t < LSEQ - 2);
            if (valid) dmax = fmaxf(dmax, acc[r]);
        }
    }
    dmax = fmaxf(dmax, __shfl_xor(dmax, 32));
    if (lhalf == 0 && dcol < DFILT)
        sent[n * DFILT + dcol] = tanhf(dmax + bcv);
}

// ---------------- kernel 1: 512 thr, 8 waves x 1 d-tile, sequential-stage dbuf ------------
__global__ __launch_bounds__(512, 4) void pcnn_conv_sent(
    const unsigned char* __restrict__ emb,
    const ushort_t* __restrict__ Bfrag, const float* __restrict__ bc,
    float* __restrict__ sent, int sent_base) {

    __shared__ __align__(16) unsigned char sembA[LROWS * 128];
    __shared__ __align__(16) unsigned char sembB[LROWS * 128];

    const int nl0  = blockIdx.x * SPB;              // pass-local first sentence
    const int tid  = threadIdx.x;
    const int wv   = tid >> 6;
    const int lane = tid & 63;
    const int lhalf = lane >> 5;
    const int l31   = lane & 31;
    const int dcol  = wv * 32 + l31;

    // B fragments: this wave's single 32-wide d-tile
    bf16x8 Bf[KSTEPS];
    #pragma unroll
    for (int ks = 0; ks < KSTEPS; ++ks) {
        int c = ks * 2 + lhalf;
        Bf[ks] = *reinterpret_cast<const bf16x8*>(Bfrag + ((c * 256 + dcol) << 3));
    }
    const float bcv = (dcol < DFILT) ? bc[dcol] : 0.0f;

    // zero pad rows 120..129 of both buffers (staging never touches them)
    if (tid < 160) {
        int b = tid / 80, j = tid % 80;
        unsigned char* base = (b == 0 ? sembA : sembB) + 120 * 128;
        reinterpret_cast<uint4*>(base)[j] = uint4{0, 0, 0, 0};
    }

    // prologue: stage sentence 0 into A
    issue_stage(sembA, emb + (size_t)nl0 * SENT_BYTES, tid);
    __syncthreads();

    #pragma unroll
    for (int s = 0; s < SPB; ++s) {
        unsigned char* cur = (s & 1) ? sembB : sembA;
        unsigned char* nxt = (s & 1) ? sembA : sembB;
        if (s + 1 < SPB)
            issue_stage(nxt, emb + (size_t)(nl0 + s + 1) * SENT_BYTES, tid);
        conv_compute(cur, sent_base + nl0 + s, Bf, bcv, sent, dcol, lhalf, l31);
        __syncthreads();   // drains vmcnt -> nxt fully landed; cur free for rewrite
    }
}

// ---------------- kernel 2: per-bag attention + scores + diag softmax ----------------
#define MAXNS 32
#define CPAD 56
__global__ __launch_bounds__(256) void pcnn_bag(
    const float* __restrict__ sent, const float* __restrict__ Wr, const float* __restrict__ br,
    const int* __restrict__ tshape, float* __restrict__ out) {

    __shared__ float s_sent[MAXNS * DFILT];
    __shared__ float s_Wr[NCLS * DFILT];
    __shared__ float s_e[MAXNS * CPAD];
    __shared__ float s_alpha[MAXNS * CPAD];
    __shared__ float s_sc[NCLS * NCLS];
    __shared__ float s_br[CPAD];

    const int g = blockIdx.x;
    const int tid = threadIdx.x;
    int start = tshape[g], end = tshape[g + 1];
    int ns = end - start;
    if (ns > MAXNS) ns = MAXNS;

    {
        int n2 = ns * (DFILT / 2);
        const float2* src = reinterpret_cast<const float2*>(sent + start * DFILT);
        for (int idx = tid; idx < n2; idx += 256)
            reinterpret_cast<float2*>(s_sent)[idx] = src[idx];
        const float2* wsrc = reinterpret_cast<const float2*>(Wr);
        for (int idx = tid; idx < (NCLS * DFILT) / 2; idx += 256)
            reinterpret_cast<float2*>(s_Wr)[idx] = wsrc[idx];
        if (tid < NCLS) s_br[tid] = br[tid];
    }
    __syncthreads();

    if (tid < 224) {
        int i0 = tid / 14, c0 = tid % 14;
        float a00 = 0, a01 = 0, a02 = 0, a03 = 0;
        float a10 = 0, a11 = 0, a12 = 0, a13 = 0;
        const float* s0p = s_sent + (2 * i0) * DFILT;
        const float* s1p = s_sent + (2 * i0 + 1) * DFILT;
        const float* w0p = s_Wr + (4 * c0 + 0) * DFILT;
        const float* w1p = s_Wr + (4 * c0 + 1) * DFILT;
        const float* w2p = (4 * c0 + 2 < NCLS) ? s_Wr + (4 * c0 + 2) * DFILT : s_Wr;
        const float* w3p = (4 * c0 + 3 < NCLS) ? s_Wr + (4 * c0 + 3) * DFILT : s_Wr;
        for (int d = 0; d < DFILT; ++d) {
            float s0 = s0p[d], s1 = s1p[d];
            float w0 = w0p[d], w1 = w1p[d], w2 = w2p[d], w3 = w3p[d];
            a00 = fmaf(s0, w0, a00); a01 = fmaf(s0, w1, a01);
            a02 = fmaf(s0, w2, a02); a03 = fmaf(s0, w3, a03);
            a10 = fmaf(s1, w0, a10); a11 = fmaf(s1, w1, a11);
            a12 = fmaf(s1, w2, a12); a13 = fmaf(s1, w3, a13);
        }
        float av[2][4] = {{a00, a01, a02, a03}, {a10, a11, a12, a13}};
        #pragma unroll
        for (int ii = 0; ii < 2; ++ii) {
            int i = 2 * i0 + ii;
            #pragma unroll
            for (int jj = 0; jj < 4; ++jj) {
                int c = 4 * c0 + jj;
                if (i < ns && c < NCLS) s_e[i * CPAD + c] = av[ii][jj] + s_br[c];
            }
        }
    }
    __syncthreads();

    if (tid < NCLS) {
        int c = tid;
        float m = -1e30f;
        for (int i = 0; i < ns; ++i) m = fmaxf(m, s_e[i * CPAD + c]);
        float den = 0.0f;
        for (int i = 0; i < ns; ++i) {
            float ex = expf(s_e[i * CPAD + c] - m);
            s_alpha[i * CPAD + c] = ex;
            den += ex;
        }
        float inv = 1.0f / den;
        for (int i = 0; i < ns; ++i) s_alpha[i * CPAD + c] *= inv;
    }
    __syncthreads();

    for (int task = tid; task < NCLS * 14; task += 256) {
        int c = task / 14, k0 = (task % 14) * 4;
        float b0 = s_br[k0], b1 = (k0+1<NCLS)?s_br[k0+1]:0.f, b2 = (k0+2<NCLS)?s_br[k0+2]:0.f, b3 = (k0+3<NCLS)?s_br[k0+3]:0.f;
        float a0 = 0, a1 = 0, a2 = 0, a3 = 0;
        for (int i = 0; i < ns; ++i) {
            float al = s_alpha[i * CPAD + c];
            const float* ep = s_e + i * CPAD + k0;
            a0 = fmaf(al, ep[0] - b0, a0);
            a1 = fmaf(al, (k0+1<NCLS?ep[1]:0.f) - b1, a1);
            a2 = fmaf(al, (k0+2<NCLS?ep[2]:0.f) - b2, a2);
            a3 = fmaf(al, (k0+3<NCLS?ep[3]:0.f) - b3, a3);
        }
        if (k0 + 0 < NCLS) s_sc[c * NCLS + k0 + 0] = a0 + b0;
        if (k0 + 1 < NCLS) s_sc[c * NCLS + k0 + 1] = a1 + b1;
        if (k0 + 2 < NCLS) s_sc[c * NCLS + k0 + 2] = a2 + b2;
        if (k0 + 3 < NCLS) s_sc[c * NCLS + k0 + 3] = a3 + b3;
    }
    __syncthreads();

    if (tid < NCLS) {
        int c = tid;
        float m = -1e30f;
        for (int k = 0; k < NCLS; ++k) m = fmaxf(m, s_sc[c * NCLS + k]);
        float den = 0.0f;
        for (int k = 0; k < NCLS; ++k) den += expf(s_sc[c * NCLS + k] - m);
        out[g * NCLS + c] = expf(s_sc[c * NCLS + c] - m) / den;
    }
}

extern "C" void kernel_launch(void* const* d_in, const int* in_sizes, int n_in,
                              void* d_out, int out_size, void* d_ws, size_t ws_size,
                              hipStream_t stream) {
    const int*   x   = (const int*)d_in[0];
    const int*   ldi = (const int*)d_in[1];
    const int*   rdi = (const int*)d_in[2];
    const int*   ts  = (const int*)d_in[3];
    const float* Wv  = (const float*)d_in[4];
    const float* pf1 = (const float*)d_in[5];
    const float* pf2 = (const float*)d_in[6];
    const float* Wc  = (const float*)d_in[7];
    const float* bc  = (const float*)d_in[8];
    const float* Wr  = (const float*)d_in[9];
    const float* br  = (const float*)d_in[10];
    float* out = (float*)d_out;

    char* ws = (char*)d_ws;
    ushort_t* Bfrag = (ushort_t*)(ws + OFF_BFRAG);
    ushort_t* Wv64  = (ushort_t*)(ws + OFF_WV64);
    ushort_t* pf1b  = (ushort_t*)(ws + OFF_PF1B);
    ushort_t* pf2b  = (ushort_t*)(ws + OFF_PF2B);
    float*    sent  = (float*)(ws + OFF_SENT);
    unsigned char* embT = (unsigned char*)(ws + OFF_EMB);

    // pick pass count so the emb image buffer fits d_ws (deterministic: ws_size fixed)
    int npass;
    if      (ws_size >= (size_t)OFF_EMB + (size_t)8192 * SENT_BYTES) npass = 1;
    else if (ws_size >= (size_t)OFF_EMB + (size_t)4096 * SENT_BYTES) npass = 2;
    else if (ws_size >= (size_t)OFF_EMB + (size_t)2048 * SENT_BYTES) npass = 4;
    else                                                             npass = 8;
    const int sper = NSENT / npass;

    pcnn_prep_b<<<(BFRAG_ELEMS + 255) / 256, 256, 0, stream>>>(Wc, pf1, pf2, Bfrag, pf1b, pf2b);
    pcnn_prep_wv<<<(80000 * 64) / 256, 256, 0, stream>>>(Wv, Wv64);

    for (int p = 0; p < npass; ++p) {
        int row_base = p * sper * LSEQ;
        int nrows = sper * LSEQ;
        pcnn_gather<<<(nrows + 255) / 256, 256, 0, stream>>>(
            x, ldi, rdi, Wv64, pf1b, pf2b, embT, row_base, nrows);
        pcnn_conv_sent<<<sper / SPB, 512, 0, stream>>>(
            embT, Bfrag, bc, sent, p * sper);
    }
    pcnn_bag<<<GBAGS, 256, 0, stream>>>(sent, Wr, br, ts, out);
}

// Round 8
// 176.921 us; speedup vs baseline: 1.2432x; 1.2432x over previous
//
#include <hip/hip_runtime.h>
#include <hip/hip_bf16.h>

typedef __bf16 bf16x8 __attribute__((ext_vector_type(8)));
typedef float f32x16 __attribute__((ext_vector_type(16)));
typedef unsigned short ushort_t;

#define NSENT 8192
#define LSEQ  120
#define GBAGS 256
#define WDIM_ 50
#define DFILT 230
#define NCLS  53
#define KSTEPS 12
#define BFRAG_ELEMS (24*256*8)
#define SPB 8                       // sentences per block
#define CH_STRIDE 2080              // 130 rows * 16 B per chunk
#define SENT_IMG  16640             // 8 chunks * 2080 B
#define IMG_CHUNKS 1040             // 16-B chunks per sentence image

// workspace byte offsets
#define OFF_BFRAG 0
#define OFF_WV64  196608
#define OFF_PF1B  (OFF_WV64 + 10240000)
#define OFF_PF2B  (OFF_PF1B + 2048)
#define OFF_SENT  (OFF_PF2B + 2048)
#define OFF_EMB   (OFF_SENT + 7536640)

static __device__ __forceinline__ ushort_t f2bf(float f) {
    unsigned int u = __float_as_uint(f);
    unsigned int lsb = (u >> 16) & 1u;
    u += 0x7fffu + lsb;
    return (ushort_t)(u >> 16);
}

// async global->LDS, 16B/lane; per-lane global addr, lane-linear LDS dest
static __device__ __forceinline__ void gll16(const void* g, void* l) {
    __builtin_amdgcn_global_load_lds(
        (const __attribute__((address_space(1))) unsigned int*)g,
        (__attribute__((address_space(3))) unsigned int*)l, 16, 0, 0);
}

// ---------------- prep 0: Wc -> MFMA B-fragment layout; pf1/pf2 -> bf16 ----------------
__global__ __launch_bounds__(256) void pcnn_prep_b(const float* __restrict__ Wc,
                                                   const float* __restrict__ pf1,
                                                   const float* __restrict__ pf2,
                                                   ushort_t* __restrict__ Bfrag,
                                                   ushort_t* __restrict__ pf1b,
                                                   ushort_t* __restrict__ pf2b) {
    int idx = blockIdx.x * 256 + threadIdx.x;
    if (idx < 1010) pf1b[idx] = f2bf(pf1[idx]);
    else if (idx < 2020) pf2b[idx - 1010] = f2bf(pf2[idx - 1010]);
    if (idx >= BFRAG_ELEMS) return;
    int c   = idx >> 11;
    int rem = idx & 2047;
    int d   = rem >> 3;
    int j   = rem & 7;
    int k   = c * 8 + j;
    int dh  = k >> 6;
    int w   = k & 63;
    float val = (d < DFILT && w < 60) ? Wc[(d * 3 + dh) * 60 + w] : 0.0f;
    Bfrag[idx] = f2bf(val);
}

// ---------------- prep 1: Wv (80000x50 fp32) -> Wv64 (80000x64 bf16, zero-padded) --------
__global__ __launch_bounds__(256) void pcnn_prep_wv(const float* __restrict__ Wv,
                                                    ushort_t* __restrict__ Wv64) {
    int idx = blockIdx.x * 256 + threadIdx.x;   // 5,120,000 total
    int r = idx >> 6, k = idx & 63;
    float val = (k < WDIM_) ? Wv[r * WDIM_ + k] : 0.0f;
    Wv64[idx] = f2bf(val);
}

// ---------------- gather: materialize chunk-major sentence images -----------------------
// image layout: [chunk 0..7][row 0..129] x 16 B; rows 120..129 zeroed.
__global__ __launch_bounds__(256) void pcnn_gather(
    const int* __restrict__ x, const int* __restrict__ ld, const int* __restrict__ rd,
    const ushort_t* __restrict__ Wv64, const ushort_t* __restrict__ pf1b,
    const ushort_t* __restrict__ pf2b,
    unsigned char* __restrict__ emb, int sent0, int nsent) {
    int idx = blockIdx.x * 256 + threadIdx.x;     // over nsent*130
    if (idx >= nsent * 130) return;
    int nl = idx / 130;
    int l  = idx - nl * 130;
    unsigned char* base = emb + (size_t)nl * SENT_IMG + l * 16;

    if (l >= LSEQ) {                               // pad rows: zeros in all 8 chunks
        uint4 z{0, 0, 0, 0};
        #pragma unroll
        for (int c = 0; c < 8; ++c)
            *reinterpret_cast<uint4*>(base + c * CH_STRIDE) = z;
        return;
    }
    int g = (sent0 + nl) * LSEQ + l;
    int tok = x[g], lp = ld[g], rp = rd[g];

    const uint4* wrow = reinterpret_cast<const uint4*>(Wv64 + (size_t)tok * 64);
    uint4 c0 = wrow[0], c1 = wrow[1], c2 = wrow[2];
    uint4 c3 = wrow[3], c4 = wrow[4], c5 = wrow[5];
    unsigned int wv4849 = *reinterpret_cast<const unsigned int*>(Wv64 + (size_t)tok * 64 + 48);
    ushort_t p10 = pf1b[lp * 5 + 0], p11 = pf1b[lp * 5 + 1], p12 = pf1b[lp * 5 + 2];
    ushort_t p13 = pf1b[lp * 5 + 3], p14 = pf1b[lp * 5 + 4];
    ushort_t p20 = pf2b[rp * 5 + 0], p21 = pf2b[rp * 5 + 1], p22 = pf2b[rp * 5 + 2];
    ushort_t p23 = pf2b[rp * 5 + 3], p24 = pf2b[rp * 5 + 4];

    uint4 c6, c7;
    c6.x = wv4849;
    c6.y = (unsigned int)p10 | ((unsigned int)p11 << 16);
    c6.z = (unsigned int)p12 | ((unsigned int)p13 << 16);
    c6.w = (unsigned int)p14 | ((unsigned int)p20 << 16);
    c7.x = (unsigned int)p21 | ((unsigned int)p22 << 16);
    c7.y = (unsigned int)p23 | ((unsigned int)p24 << 16);
    c7.z = 0; c7.w = 0;

    *reinterpret_cast<uint4*>(base + 0 * CH_STRIDE) = c0;
    *reinterpret_cast<uint4*>(base + 1 * CH_STRIDE) = c1;
    *reinterpret_cast<uint4*>(base + 2 * CH_STRIDE) = c2;
    *reinterpret_cast<uint4*>(base + 3 * CH_STRIDE) = c3;
    *reinterpret_cast<uint4*>(base + 4 * CH_STRIDE) = c4;
    *reinterpret_cast<uint4*>(base + 5 * CH_STRIDE) = c5;
    *reinterpret_cast<uint4*>(base + 6 * CH_STRIDE) = c6;
    *reinterpret_cast<uint4*>(base + 7 * CH_STRIDE) = c7;
}

// ---------------- conv staging: fully linear global_load_lds (1040 chunks) --------------
__device__ __forceinline__ void issue_stage(unsigned char* __restrict__ buf,
                                            const unsigned char* __restrict__ embS, int tid) {
    gll16(embS + tid * 16,          buf + tid * 16);
    gll16(embS + (tid + 256) * 16,  buf + (tid + 256) * 16);
    gll16(embS + (tid + 512) * 16,  buf + (tid + 512) * 16);
    gll16(embS + (tid + 768) * 16,  buf + (tid + 768) * 16);
    if (tid < IMG_CHUNKS - 1024)
        gll16(embS + (tid + 1024) * 16, buf + (tid + 1024) * 16);
}

// ---------------- kernel 1: 256 thr, 4 waves x 2 d-tiles, chunk-major LDS ----------------
__global__ __launch_bounds__(256, 3) void pcnn_conv_sent(
    const unsigned char* __restrict__ emb,
    const ushort_t* __restrict__ Bfrag, const float* __restrict__ bc,
    float* __restrict__ sent, int sent_base) {

    __shared__ __align__(16) unsigned char sembA[SENT_IMG];
    __shared__ __align__(16) unsigned char sembB[SENT_IMG];

    const int nl0  = blockIdx.x * SPB;              // pass-local first sentence
    const int tid  = threadIdx.x;
    const int wv   = tid >> 6;
    const int lane = tid & 63;
    const int lhalf = lane >> 5;
    const int l31   = lane & 31;
    const int dcol0 = wv * 64 + l31;
    const int dcol1 = wv * 64 + 32 + l31;

    // B fragments: this wave's two 32-wide d-tiles
    bf16x8 Bf[2][KSTEPS];
    #pragma unroll
    for (int ks = 0; ks < KSTEPS; ++ks) {
        int c = ks * 2 + lhalf;
        Bf[0][ks] = *reinterpret_cast<const bf16x8*>(Bfrag + ((c * 256 + dcol0) << 3));
        Bf[1][ks] = *reinterpret_cast<const bf16x8*>(Bfrag + ((c * 256 + dcol1) << 3));
    }
    const float bcv0 = (dcol0 < DFILT) ? bc[dcol0] : 0.0f;
    const float bcv1 = (dcol1 < DFILT) ? bc[dcol1] : 0.0f;

    // prologue: stage sentence 0 into A
    issue_stage(sembA, emb + (size_t)nl0 * SENT_IMG, tid);
    __syncthreads();

    #pragma unroll
    for (int s = 0; s < SPB; ++s) {
        unsigned char* cur = (s & 1) ? sembB : sembA;
        unsigned char* nxt = (s & 1) ? sembA : sembB;
        if (s + 1 < SPB)
            issue_stage(nxt, emb + (size_t)(nl0 + s + 1) * SENT_IMG, tid);

        float dmax0 = -1e30f, dmax1 = -1e30f;
        #pragma unroll
        for (int tt = 0; tt < 4; ++tt) {
            f32x16 a0, a1;
            #pragma unroll
            for (int r = 0; r < 16; ++r) { a0[r] = 0.0f; a1[r] = 0.0f; }
            int trow = tt * 32 + l31;
            #pragma unroll
            for (int ks = 0; ks < KSTEPS; ++ks) {
                int dh = ks >> 2, q = ks & 3;
                int chunk = q * 2 + lhalf;
                int l = trow + dh;
                // lanes read consecutive rows at fixed chunk -> contiguous 512 B: conflict-free
                bf16x8 Af = *reinterpret_cast<const bf16x8*>(cur + chunk * CH_STRIDE + l * 16);
                a0 = __builtin_amdgcn_mfma_f32_32x32x16_bf16(Af, Bf[0][ks], a0, 0, 0, 0);
                a1 = __builtin_amdgcn_mfma_f32_32x32x16_bf16(Af, Bf[1][ks], a1, 0, 0, 0);
            }
            #pragma unroll
            for (int r = 0; r < 16; ++r) {
                int t = tt * 32 + (r & 3) + 8 * (r >> 2) + 4 * lhalf;
                bool valid = (tt < 3) || (t < LSEQ - 2);
                if (valid) { dmax0 = fmaxf(dmax0, a0[r]); dmax1 = fmaxf(dmax1, a1[r]); }
            }
        }
        dmax0 = fmaxf(dmax0, __shfl_xor(dmax0, 32));
        dmax1 = fmaxf(dmax1, __shfl_xor(dmax1, 32));
        if (lhalf == 0) {
            int n = sent_base + nl0 + s;
            if (dcol0 < DFILT) sent[n * DFILT + dcol0] = tanhf(dmax0 + bcv0);
            if (dcol1 < DFILT) sent[n * DFILT + dcol1] = tanhf(dmax1 + bcv1);
        }
        __syncthreads();   // drains vmcnt -> nxt landed; cur free for rewrite
    }
}

// ---------------- kernel 2: per-bag attention + scores + diag softmax ----------------
#define MAXNS 32
#define CPAD 56
__global__ __launch_bounds__(256) void pcnn_bag(
    const float* __restrict__ sent, const float* __restrict__ Wr, const float* __restrict__ br,
    const int* __restrict__ tshape, float* __restrict__ out) {

    __shared__ float s_sent[MAXNS * DFILT];
    __shared__ float s_Wr[NCLS * DFILT];
    __shared__ float s_e[MAXNS * CPAD];
    __shared__ float s_alpha[MAXNS * CPAD];
    __shared__ float s_sc[NCLS * NCLS];
    __shared__ float s_br[CPAD];

    const int g = blockIdx.x;
    const int tid = threadIdx.x;
    int start = tshape[g], end = tshape[g + 1];
    int ns = end - start;
    if (ns > MAXNS) ns = MAXNS;

    {
        int n2 = ns * (DFILT / 2);
        const float2* src = reinterpret_cast<const float2*>(sent + start * DFILT);
        for (int idx = tid; idx < n2; idx += 256)
            reinterpret_cast<float2*>(s_sent)[idx] = src[idx];
        const float2* wsrc = reinterpret_cast<const float2*>(Wr);
        for (int idx = tid; idx < (NCLS * DFILT) / 2; idx += 256)
            reinterpret_cast<float2*>(s_Wr)[idx] = wsrc[idx];
        if (tid < NCLS) s_br[tid] = br[tid];
    }
    __syncthreads();

    if (tid < 224) {
        int i0 = tid / 14, c0 = tid % 14;
        float a00 = 0, a01 = 0, a02 = 0, a03 = 0;
        float a10 = 0, a11 = 0, a12 = 0, a13 = 0;
        const float* s0p = s_sent + (2 * i0) * DFILT;
        const float* s1p = s_sent + (2 * i0 + 1) * DFILT;
        const float* w0p = s_Wr + (4 * c0 + 0) * DFILT;
        const float* w1p = s_Wr + (4 * c0 + 1) * DFILT;
        const float* w2p = (4 * c0 + 2 < NCLS) ? s_Wr + (4 * c0 + 2) * DFILT : s_Wr;
        const float* w3p = (4 * c0 + 3 < NCLS) ? s_Wr + (4 * c0 + 3) * DFILT : s_Wr;
        for (int d = 0; d < DFILT; ++d) {
            float s0 = s0p[d], s1 = s1p[d];
            float w0 = w0p[d], w1 = w1p[d], w2 = w2p[d], w3 = w3p[d];
            a00 = fmaf(s0, w0, a00); a01 = fmaf(s0, w1, a01);
            a02 = fmaf(s0, w2, a02); a03 = fmaf(s0, w3, a03);
            a10 = fmaf(s1, w0, a10); a11 = fmaf(s1, w1, a11);
            a12 = fmaf(s1, w2, a12); a13 = fmaf(s1, w3, a13);
        }
        float av[2][4] = {{a00, a01, a02, a03}, {a10, a11, a12, a13}};
        #pragma unroll
        for (int ii = 0; ii < 2; ++ii) {
            int i = 2 * i0 + ii;
            #pragma unroll
            for (int jj = 0; jj < 4; ++jj) {
                int c = 4 * c0 + jj;
                if (i < ns && c < NCLS) s_e[i * CPAD + c] = av[ii][jj] + s_br[c];
            }
        }
    }
    __syncthreads();

    if (tid < NCLS) {
        int c = tid;
        float m = -1e30f;
        for (int i = 0; i < ns; ++i) m = fmaxf(m, s_e[i * CPAD + c]);
        float den = 0.0f;
        for (int i = 0; i < ns; ++i) {
            float ex = expf(s_e[i * CPAD + c] - m);
            s_alpha[i * CPAD + c] = ex;
            den += ex;
        }
        float inv = 1.0f / den;
        for (int i = 0; i < ns; ++i) s_alpha[i * CPAD + c] *= inv;
    }
    __syncthreads();

    for (int task = tid; task < NCLS * 14; task += 256) {
        int c = task / 14, k0 = (task % 14) * 4;
        float b0 = s_br[k0], b1 = (k0+1<NCLS)?s_br[k0+1]:0.f, b2 = (k0+2<NCLS)?s_br[k0+2]:0.f, b3 = (k0+3<NCLS)?s_br[k0+3]:0.f;
        float a0 = 0, a1 = 0, a2 = 0, a3 = 0;
        for (int i = 0; i < ns; ++i) {
            float al = s_alpha[i * CPAD + c];
            const float* ep = s_e + i * CPAD + k0;
            a0 = fmaf(al, ep[0] - b0, a0);
            a1 = fmaf(al, (k0+1<NCLS?ep[1]:0.f) - b1, a1);
            a2 = fmaf(al, (k0+2<NCLS?ep[2]:0.f) - b2, a2);
            a3 = fmaf(al, (k0+3<NCLS?ep[3]:0.f) - b3, a3);
        }
        if (k0 + 0 < NCLS) s_sc[c * NCLS + k0 + 0] = a0 + b0;
        if (k0 + 1 < NCLS) s_sc[c * NCLS + k0 + 1] = a1 + b1;
        if (k0 + 2 < NCLS) s_sc[c * NCLS + k0 + 2] = a2 + b2;
        if (k0 + 3 < NCLS) s_sc[c * NCLS + k0 + 3] = a3 + b3;
    }
    __syncthreads();

    if (tid < NCLS) {
        int c = tid;
        float m = -1e30f;
        for (int k = 0; k < NCLS; ++k) m = fmaxf(m, s_sc[c * NCLS + k]);
        float den = 0.0f;
        for (int k = 0; k < NCLS; ++k) den += expf(s_sc[c * NCLS + k] - m);
        out[g * NCLS + c] = expf(s_sc[c * NCLS + c] - m) / den;
    }
}

extern "C" void kernel_launch(void* const* d_in, const int* in_sizes, int n_in,
                              void* d_out, int out_size, void* d_ws, size_t ws_size,
                              hipStream_t stream) {
    const int*   x   = (const int*)d_in[0];
    const int*   ldi = (const int*)d_in[1];
    const int*   rdi = (const int*)d_in[2];
    const int*   ts  = (const int*)d_in[3];
    const float* Wv  = (const float*)d_in[4];
    const float* pf1 = (const float*)d_in[5];
    const float* pf2 = (const float*)d_in[6];
    const float* Wc  = (const float*)d_in[7];
    const float* bc  = (const float*)d_in[8];
    const float* Wr  = (const float*)d_in[9];
    const float* br  = (const float*)d_in[10];
    float* out = (float*)d_out;

    char* ws = (char*)d_ws;
    ushort_t* Bfrag = (ushort_t*)(ws + OFF_BFRAG);
    ushort_t* Wv64  = (ushort_t*)(ws + OFF_WV64);
    ushort_t* pf1b  = (ushort_t*)(ws + OFF_PF1B);
    ushort_t* pf2b  = (ushort_t*)(ws + OFF_PF2B);
    float*    sent  = (float*)(ws + OFF_SENT);
    unsigned char* embT = (unsigned char*)(ws + OFF_EMB);

    int npass;
    if      (ws_size >= (size_t)OFF_EMB + (size_t)8192 * SENT_IMG) npass = 1;
    else if (ws_size >= (size_t)OFF_EMB + (size_t)4096 * SENT_IMG) npass = 2;
    else if (ws_size >= (size_t)OFF_EMB + (size_t)2048 * SENT_IMG) npass = 4;
    else                                                           npass = 8;
    const int sper = NSENT / npass;

    pcnn_prep_b<<<(BFRAG_ELEMS + 255) / 256, 256, 0, stream>>>(Wc, pf1, pf2, Bfrag, pf1b, pf2b);
    pcnn_prep_wv<<<(80000 * 64) / 256, 256, 0, stream>>>(Wv, Wv64);

    for (int p = 0; p < npass; ++p) {
        int nrows = sper * 130;
        pcnn_gather<<<(nrows + 255) / 256, 256, 0, stream>>>(
            x, ldi, rdi, Wv64, pf1b, pf2b, embT, p * sper, sper);
        pcnn_conv_sent<<<sper / SPB, 256, 0, stream>>>(
            embT, Bfrag, bc, sent, p * sper);
    }
    pcnn_bag<<<GBAGS, 256, 0, stream>>>(sent, Wr, br, ts, out);
}

// Round 9
// 160.843 us; speedup vs baseline: 1.3675x; 1.1000x over previous
//
#include <hip/hip_runtime.h>
#include <hip/hip_bf16.h>

typedef __bf16 bf16x8 __attribute__((ext_vector_type(8)));
typedef float f32x16 __attribute__((ext_vector_type(16)));
typedef unsigned short ushort_t;

#define NSENT 8192
#define LSEQ  120
#define GBAGS 256
#define WDIM_ 50
#define DFILT 230
#define NCLS  53
#define KSTEPS 12
#define BFRAG_ELEMS (24*256*8)
#define SPB 8                       // sentences per block
#define CH_STRIDE 2080              // 130 rows * 16 B per chunk
#define SENT_IMG  16640             // 8 chunks * 2080 B (single LDS buffer)

// workspace byte offsets
#define OFF_BFRAG 0
#define OFF_WV64  196608
#define OFF_PF1B  (OFF_WV64 + 10240000)
#define OFF_PF2B  (OFF_PF1B + 2048)
#define OFF_SENT  (OFF_PF2B + 2048)
#define OFF_TAIL  (OFF_SENT + 7536640)   // TailT: 983040 * 32 B = 31.4 MB

static __device__ __forceinline__ ushort_t f2bf(float f) {
    unsigned int u = __float_as_uint(f);
    unsigned int lsb = (u >> 16) & 1u;
    u += 0x7fffu + lsb;
    return (ushort_t)(u >> 16);
}

// ---------------- prep 0: Wc -> MFMA B-fragment layout; pf1/pf2 -> bf16 ----------------
__global__ __launch_bounds__(256) void pcnn_prep_b(const float* __restrict__ Wc,
                                                   const float* __restrict__ pf1,
                                                   const float* __restrict__ pf2,
                                                   ushort_t* __restrict__ Bfrag,
                                                   ushort_t* __restrict__ pf1b,
                                                   ushort_t* __restrict__ pf2b) {
    int idx = blockIdx.x * 256 + threadIdx.x;
    if (idx < 1010) pf1b[idx] = f2bf(pf1[idx]);
    else if (idx < 2020) pf2b[idx - 1010] = f2bf(pf2[idx - 1010]);
    if (idx >= BFRAG_ELEMS) return;
    int c   = idx >> 11;
    int rem = idx & 2047;
    int d   = rem >> 3;
    int j   = rem & 7;
    int k   = c * 8 + j;
    int dh  = k >> 6;
    int w   = k & 63;
    float val = (d < DFILT && w < 60) ? Wc[(d * 3 + dh) * 60 + w] : 0.0f;
    Bfrag[idx] = f2bf(val);
}

// ---------------- prep 1: Wv (80000x50 fp32) -> Wv64 (80000x64 bf16, zero-padded) --------
__global__ __launch_bounds__(256) void pcnn_prep_wv(const float* __restrict__ Wv,
                                                    ushort_t* __restrict__ Wv64) {
    int idx = blockIdx.x * 256 + threadIdx.x;   // 5,120,000 total
    int r = idx >> 6, k = idx & 63;
    float val = (k < WDIM_) ? Wv[r * WDIM_ + k] : 0.0f;
    Wv64[idx] = f2bf(val);
}

// ---------------- prep 2: materialize spliced 32B tails (chunks 6,7) per (n,l) ----------
__global__ __launch_bounds__(256) void pcnn_prep_tail(
    const int* __restrict__ x, const int* __restrict__ ld, const int* __restrict__ rd,
    const ushort_t* __restrict__ Wv64, const ushort_t* __restrict__ pf1b,
    const ushort_t* __restrict__ pf2b, ushort_t* __restrict__ TailT) {
    int idx = blockIdx.x * 256 + threadIdx.x;   // 983,040 total
    if (idx >= NSENT * LSEQ) return;
    int tok = x[idx], lp = ld[idx], rp = rd[idx];
    ushort_t u[16];
    *reinterpret_cast<unsigned int*>(&u[0]) =
        *reinterpret_cast<const unsigned int*>(Wv64 + (size_t)tok * 64 + 48);
    u[2] = pf1b[lp * 5 + 0]; u[3] = pf1b[lp * 5 + 1]; u[4] = pf1b[lp * 5 + 2];
    u[5] = pf1b[lp * 5 + 3]; u[6] = pf1b[lp * 5 + 4];
    u[7] = pf2b[rp * 5 + 0];
    u[8] = pf2b[rp * 5 + 1]; u[9] = pf2b[rp * 5 + 2];
    u[10] = pf2b[rp * 5 + 3]; u[11] = pf2b[rp * 5 + 4];
    u[12] = 0; u[13] = 0; u[14] = 0; u[15] = 0;
    uint4* dst = reinterpret_cast<uint4*>(TailT + idx * 16);
    dst[0] = *reinterpret_cast<const uint4*>(&u[0]);
    dst[1] = *reinterpret_cast<const uint4*>(&u[8]);
}

// ---------------- kernel 1: fused conv; register-staged T14, chunk-major LDS -------------
// 256 thr = 4 waves x 2 d-tiles. Staging: thread (srow, sh) holds 4 uint4:
//   sh=0 -> Wv64 row bytes 0..63 (chunks 0-3); sh=1 -> bytes 64..95 + TailT 32B (chunks 4-7).
__global__ __launch_bounds__(256, 2) void pcnn_conv_sent(
    const int* __restrict__ x,
    const ushort_t* __restrict__ Wv64, const ushort_t* __restrict__ TailT,
    const ushort_t* __restrict__ Bfrag, const float* __restrict__ bc,
    float* __restrict__ sent) {

    __shared__ __align__(16) unsigned char semb[SENT_IMG];

    const int n0   = blockIdx.x * SPB;
    const int tid  = threadIdx.x;
    const int wv   = tid >> 6;
    const int lane = tid & 63;
    const int lhalf = lane >> 5;
    const int l31   = lane & 31;
    const int dcol0 = wv * 64 + l31;
    const int dcol1 = dcol0 + 32;

    const int srow = tid >> 1;
    const int sh   = tid & 1;
    const bool sact = (srow < LSEQ);

    // B fragments: this wave's two 32-wide d-tiles (L2-resident, reused by all blocks)
    bf16x8 Bf0[KSTEPS], Bf1[KSTEPS];
    #pragma unroll
    for (int ks = 0; ks < KSTEPS; ++ks) {
        int c = ks * 2 + lhalf;
        Bf0[ks] = *reinterpret_cast<const bf16x8*>(Bfrag + ((c * 256 + dcol0) << 3));
        Bf1[ks] = *reinterpret_cast<const bf16x8*>(Bfrag + ((c * 256 + dcol1) << 3));
    }
    const float bcv0 = (dcol0 < DFILT) ? bc[dcol0] : 0.0f;
    const float bcv1 = (dcol1 < DFILT) ? bc[dcol1] : 0.0f;

    // preload token ids for all SPB sentences (kills the id->row dependent chain)
    int tokv[SPB];
    #pragma unroll
    for (int s = 0; s < SPB; ++s)
        tokv[s] = sact ? x[(n0 + s) * LSEQ + srow] : 0;

    // zero pad rows 120..129 in all 8 chunks (staging never touches them)
    if (tid < 80) {
        int c = tid / 10, r = 120 + tid % 10;
        *reinterpret_cast<uint4*>(semb + c * CH_STRIDE + r * 16) = uint4{0, 0, 0, 0};
    }

    uint4 r0, r1, r2, r3;
    // prologue: load + write sentence 0
    if (sact) {
        int g = n0 * LSEQ + srow;
        const uint4* w = reinterpret_cast<const uint4*>(Wv64 + (size_t)tokv[0] * 64);
        if (sh == 0) { r0 = w[0]; r1 = w[1]; r2 = w[2]; r3 = w[3]; }
        else {
            r0 = w[4]; r1 = w[5];
            const uint4* t = reinterpret_cast<const uint4*>(TailT + (size_t)g * 16);
            r2 = t[0]; r3 = t[1];
        }
        unsigned char* p = semb + (sh * 4) * CH_STRIDE + srow * 16;
        *reinterpret_cast<uint4*>(p)                 = r0;
        *reinterpret_cast<uint4*>(p + CH_STRIDE)     = r1;
        *reinterpret_cast<uint4*>(p + 2 * CH_STRIDE) = r2;
        *reinterpret_cast<uint4*>(p + 3 * CH_STRIDE) = r3;
    }
    __syncthreads();

    #pragma unroll
    for (int s = 0; s < SPB; ++s) {
        // T14: issue next sentence's global loads BEFORE compute (latency hides under MFMA)
        if (s + 1 < SPB && sact) {
            int g = (n0 + s + 1) * LSEQ + srow;
            const uint4* w = reinterpret_cast<const uint4*>(Wv64 + (size_t)tokv[s + 1] * 64);
            if (sh == 0) { r0 = w[0]; r1 = w[1]; r2 = w[2]; r3 = w[3]; }
            else {
                r0 = w[4]; r1 = w[5];
                const uint4* t = reinterpret_cast<const uint4*>(TailT + (size_t)g * 16);
                r2 = t[0]; r3 = t[1];
            }
        }

        float dmax0 = -1e30f, dmax1 = -1e30f;
        #pragma unroll
        for (int tt = 0; tt < 4; ++tt) {
            f32x16 a0, a1;
            #pragma unroll
            for (int r = 0; r < 16; ++r) { a0[r] = 0.0f; a1[r] = 0.0f; }
            int trow = tt * 32 + l31;
            #pragma unroll
            for (int ks = 0; ks < KSTEPS; ++ks) {
                int dh = ks >> 2, q = ks & 3;
                int chunk = q * 2 + lhalf;
                int l = trow + dh;
                bf16x8 Af = *reinterpret_cast<const bf16x8*>(semb + chunk * CH_STRIDE + l * 16);
                a0 = __builtin_amdgcn_mfma_f32_32x32x16_bf16(Af, Bf0[ks], a0, 0, 0, 0);
                a1 = __builtin_amdgcn_mfma_f32_32x32x16_bf16(Af, Bf1[ks], a1, 0, 0, 0);
            }
            #pragma unroll
            for (int r = 0; r < 16; ++r) {
                int t = tt * 32 + (r & 3) + 8 * (r >> 2) + 4 * lhalf;
                bool valid = (tt < 3) || (t < LSEQ - 2);
                if (valid) { dmax0 = fmaxf(dmax0, a0[r]); dmax1 = fmaxf(dmax1, a1[r]); }
            }
        }
        dmax0 = fmaxf(dmax0, __shfl_xor(dmax0, 32));
        dmax1 = fmaxf(dmax1, __shfl_xor(dmax1, 32));
        if (lhalf == 0) {
            int n = n0 + s;
            if (dcol0 < DFILT) sent[n * DFILT + dcol0] = tanhf(dmax0 + bcv0);
            if (dcol1 < DFILT) sent[n * DFILT + dcol1] = tanhf(dmax1 + bcv1);
        }
        __syncthreads();               // all waves done reading semb for sentence s

        if (s + 1 < SPB) {
            if (sact) {
                unsigned char* p = semb + (sh * 4) * CH_STRIDE + srow * 16;
                *reinterpret_cast<uint4*>(p)                 = r0;
                *reinterpret_cast<uint4*>(p + CH_STRIDE)     = r1;
                *reinterpret_cast<uint4*>(p + 2 * CH_STRIDE) = r2;
                *reinterpret_cast<uint4*>(p + 3 * CH_STRIDE) = r3;
            }
            __syncthreads();           // sentence s+1 visible to all waves
        }
    }
}

// ---------------- kernel 2: per-bag attention + scores + diag softmax ----------------
#define MAXNS 32
#define CPAD 56
__global__ __launch_bounds__(256) void pcnn_bag(
    const float* __restrict__ sent, const float* __restrict__ Wr, const float* __restrict__ br,
    const int* __restrict__ tshape, float* __restrict__ out) {

    __shared__ float s_sent[MAXNS * DFILT];
    __shared__ float s_Wr[NCLS * DFILT];
    __shared__ float s_e[MAXNS * CPAD];
    __shared__ float s_alpha[MAXNS * CPAD];
    __shared__ float s_sc[NCLS * NCLS];
    __shared__ float s_br[CPAD];

    const int g = blockIdx.x;
    const int tid = threadIdx.x;
    int start = tshape[g], end = tshape[g + 1];
    int ns = end - start;
    if (ns > MAXNS) ns = MAXNS;

    {
        int n2 = ns * (DFILT / 2);
        const float2* src = reinterpret_cast<const float2*>(sent + start * DFILT);
        for (int idx = tid; idx < n2; idx += 256)
            reinterpret_cast<float2*>(s_sent)[idx] = src[idx];
        const float2* wsrc = reinterpret_cast<const float2*>(Wr);
        for (int idx = tid; idx < (NCLS * DFILT) / 2; idx += 256)
            reinterpret_cast<float2*>(s_Wr)[idx] = wsrc[idx];
        if (tid < NCLS) s_br[tid] = br[tid];
    }
    __syncthreads();

    if (tid < 224) {
        int i0 = tid / 14, c0 = tid % 14;
        float a00 = 0, a01 = 0, a02 = 0, a03 = 0;
        float a10 = 0, a11 = 0, a12 = 0, a13 = 0;
        const float* s0p = s_sent + (2 * i0) * DFILT;
        const float* s1p = s_sent + (2 * i0 + 1) * DFILT;
        const float* w0p = s_Wr + (4 * c0 + 0) * DFILT;
        const float* w1p = s_Wr + (4 * c0 + 1) * DFILT;
        const float* w2p = (4 * c0 + 2 < NCLS) ? s_Wr + (4 * c0 + 2) * DFILT : s_Wr;
        const float* w3p = (4 * c0 + 3 < NCLS) ? s_Wr + (4 * c0 + 3) * DFILT : s_Wr;
        for (int d = 0; d < DFILT; ++d) {
            float s0 = s0p[d], s1 = s1p[d];
            float w0 = w0p[d], w1 = w1p[d], w2 = w2p[d], w3 = w3p[d];
            a00 = fmaf(s0, w0, a00); a01 = fmaf(s0, w1, a01);
            a02 = fmaf(s0, w2, a02); a03 = fmaf(s0, w3, a03);
            a10 = fmaf(s1, w0, a10); a11 = fmaf(s1, w1, a11);
            a12 = fmaf(s1, w2, a12); a13 = fmaf(s1, w3, a13);
        }
        float av[2][4] = {{a00, a01, a02, a03}, {a10, a11, a12, a13}};
        #pragma unroll
        for (int ii = 0; ii < 2; ++ii) {
            int i = 2 * i0 + ii;
            #pragma unroll
            for (int jj = 0; jj < 4; ++jj) {
                int c = 4 * c0 + jj;
                if (i < ns && c < NCLS) s_e[i * CPAD + c] = av[ii][jj] + s_br[c];
            }
        }
    }
    __syncthreads();

    if (tid < NCLS) {
        int c = tid;
        float m = -1e30f;
        for (int i = 0; i < ns; ++i) m = fmaxf(m, s_e[i * CPAD + c]);
        float den = 0.0f;
        for (int i = 0; i < ns; ++i) {
            float ex = expf(s_e[i * CPAD + c] - m);
            s_alpha[i * CPAD + c] = ex;
            den += ex;
        }
        float inv = 1.0f / den;
        for (int i = 0; i < ns; ++i) s_alpha[i * CPAD + c] *= inv;
    }
    __syncthreads();

    for (int task = tid; task < NCLS * 14; task += 256) {
        int c = task / 14, k0 = (task % 14) * 4;
        float b0 = s_br[k0], b1 = (k0+1<NCLS)?s_br[k0+1]:0.f, b2 = (k0+2<NCLS)?s_br[k0+2]:0.f, b3 = (k0+3<NCLS)?s_br[k0+3]:0.f;
        float a0 = 0, a1 = 0, a2 = 0, a3 = 0;
        for (int i = 0; i < ns; ++i) {
            float al = s_alpha[i * CPAD + c];
            const float* ep = s_e + i * CPAD + k0;
            a0 = fmaf(al, ep[0] - b0, a0);
            a1 = fmaf(al, (k0+1<NCLS?ep[1]:0.f) - b1, a1);
            a2 = fmaf(al, (k0+2<NCLS?ep[2]:0.f) - b2, a2);
            a3 = fmaf(al, (k0+3<NCLS?ep[3]:0.f) - b3, a3);
        }
        if (k0 + 0 < NCLS) s_sc[c * NCLS + k0 + 0] = a0 + b0;
        if (k0 + 1 < NCLS) s_sc[c * NCLS + k0 + 1] = a1 + b1;
        if (k0 + 2 < NCLS) s_sc[c * NCLS + k0 + 2] = a2 + b2;
        if (k0 + 3 < NCLS) s_sc[c * NCLS + k0 + 3] = a3 + b3;
    }
    __syncthreads();

    if (tid < NCLS) {
        int c = tid;
        float m = -1e30f;
        for (int k = 0; k < NCLS; ++k) m = fmaxf(m, s_sc[c * NCLS + k]);
        float den = 0.0f;
        for (int k = 0; k < NCLS; ++k) den += expf(s_sc[c * NCLS + k] - m);
        out[g * NCLS + c] = expf(s_sc[c * NCLS + c] - m) / den;
    }
}

extern "C" void kernel_launch(void* const* d_in, const int* in_sizes, int n_in,
                              void* d_out, int out_size, void* d_ws, size_t ws_size,
                              hipStream_t stream) {
    const int*   x   = (const int*)d_in[0];
    const int*   ldi = (const int*)d_in[1];
    const int*   rdi = (const int*)d_in[2];
    const int*   ts  = (const int*)d_in[3];
    const float* Wv  = (const float*)d_in[4];
    const float* pf1 = (const float*)d_in[5];
    const float* pf2 = (const float*)d_in[6];
    const float* Wc  = (const float*)d_in[7];
    const float* bc  = (const float*)d_in[8];
    const float* Wr  = (const float*)d_in[9];
    const float* br  = (const float*)d_in[10];
    float* out = (float*)d_out;

    char* ws = (char*)d_ws;
    ushort_t* Bfrag = (ushort_t*)(ws + OFF_BFRAG);
    ushort_t* Wv64  = (ushort_t*)(ws + OFF_WV64);
    ushort_t* pf1b  = (ushort_t*)(ws + OFF_PF1B);
    ushort_t* pf2b  = (ushort_t*)(ws + OFF_PF2B);
    float*    sent  = (float*)(ws + OFF_SENT);
    ushort_t* TailT = (ushort_t*)(ws + OFF_TAIL);

    pcnn_prep_b<<<(BFRAG_ELEMS + 255) / 256, 256, 0, stream>>>(Wc, pf1, pf2, Bfrag, pf1b, pf2b);
    pcnn_prep_wv<<<(80000 * 64) / 256, 256, 0, stream>>>(Wv, Wv64);
    pcnn_prep_tail<<<(NSENT * LSEQ + 255) / 256, 256, 0, stream>>>(x, ldi, rdi, Wv64, pf1b, pf2b, TailT);
    pcnn_conv_sent<<<NSENT / SPB, 256, 0, stream>>>(x, Wv64, TailT, Bfrag, bc, sent);
    pcnn_bag<<<GBAGS, 256, 0, stream>>>(sent, Wr, br, ts, out);
}

// Round 10
// 158.519 us; speedup vs baseline: 1.3876x; 1.0147x over previous
//
#include <hip/hip_runtime.h>
#include <hip/hip_bf16.h>

typedef __bf16 bf16x8 __attribute__((ext_vector_type(8)));
typedef float f32x16 __attribute__((ext_vector_type(16)));
typedef unsigned short ushort_t;

#define NSENT 8192
#define LSEQ  120
#define GBAGS 256
#define WDIM_ 50
#define DFILT 230
#define NCLS  53
#define KSTEPS 12
#define BFRAG_ELEMS (24*256*8)
#define SPB 4                       // sentences per block (grid 2048)
#define CH_STRIDE 2080              // 130 rows * 16 B per chunk
#define SENT_IMG  16640             // 8 chunks * 2080 B per LDS buffer

// workspace byte offsets
#define OFF_BFRAG 0
#define OFF_WV64  196608
#define OFF_PF1B  (OFF_WV64 + 10240000)
#define OFF_PF2B  (OFF_PF1B + 2048)
#define OFF_SENT  (OFF_PF2B + 2048)
#define OFF_TAIL  (OFF_SENT + 7536640)   // TailT: 983040 * 32 B = 31.4 MB (pf-only)

static __device__ __forceinline__ ushort_t f2bf(float f) {
    unsigned int u = __float_as_uint(f);
    unsigned int lsb = (u >> 16) & 1u;
    u += 0x7fffu + lsb;
    return (ushort_t)(u >> 16);
}

// ---------------- prep 0: Wc -> MFMA B-fragment layout; pf1/pf2 -> bf16 ----------------
__global__ __launch_bounds__(256) void pcnn_prep_b(const float* __restrict__ Wc,
                                                   const float* __restrict__ pf1,
                                                   const float* __restrict__ pf2,
                                                   ushort_t* __restrict__ Bfrag,
                                                   ushort_t* __restrict__ pf1b,
                                                   ushort_t* __restrict__ pf2b) {
    int idx = blockIdx.x * 256 + threadIdx.x;
    if (idx < 1010) pf1b[idx] = f2bf(pf1[idx]);
    else if (idx < 2020) pf2b[idx - 1010] = f2bf(pf2[idx - 1010]);
    if (idx >= BFRAG_ELEMS) return;
    int c   = idx >> 11;
    int rem = idx & 2047;
    int d   = rem >> 3;
    int j   = rem & 7;
    int k   = c * 8 + j;
    int dh  = k >> 6;
    int w   = k & 63;
    float val = (d < DFILT && w < 60) ? Wc[(d * 3 + dh) * 60 + w] : 0.0f;
    Bfrag[idx] = f2bf(val);
}

// ---------------- prep 1: Wv (80000x50 fp32) -> Wv64 (80000x64 bf16, zero-padded) --------
__global__ __launch_bounds__(256) void pcnn_prep_wv(const float* __restrict__ Wv,
                                                    ushort_t* __restrict__ Wv64) {
    int idx = blockIdx.x * 256 + threadIdx.x;   // 5,120,000 total
    int r = idx >> 6, k = idx & 63;
    float val = (k < WDIM_) ? Wv[r * WDIM_ + k] : 0.0f;
    Wv64[idx] = f2bf(val);
}

// ---------------- prep 2: pf-only tails per (n,l); NO Wv access (conv ORs w[6] in) -------
// t0 = [0,0, pf1_0..4, pf2_0]  (bytes 0-3 zero: OR target for wv48,wv49)
// t1 = [pf2_1..4, 0,0,0,0]
__global__ __launch_bounds__(256) void pcnn_prep_tail(
    const int* __restrict__ ld, const int* __restrict__ rd,
    const ushort_t* __restrict__ pf1b, const ushort_t* __restrict__ pf2b,
    ushort_t* __restrict__ TailT) {
    int idx = blockIdx.x * 256 + threadIdx.x;   // 983,040 total
    if (idx >= NSENT * LSEQ) return;
    int lp = ld[idx], rp = rd[idx];
    ushort_t u[16];
    u[0] = 0; u[1] = 0;
    u[2] = pf1b[lp * 5 + 0]; u[3] = pf1b[lp * 5 + 1]; u[4] = pf1b[lp * 5 + 2];
    u[5] = pf1b[lp * 5 + 3]; u[6] = pf1b[lp * 5 + 4];
    u[7] = pf2b[rp * 5 + 0];
    u[8] = pf2b[rp * 5 + 1]; u[9] = pf2b[rp * 5 + 2];
    u[10] = pf2b[rp * 5 + 3]; u[11] = pf2b[rp * 5 + 4];
    u[12] = 0; u[13] = 0; u[14] = 0; u[15] = 0;
    uint4* dst = reinterpret_cast<uint4*>(TailT + idx * 16);
    dst[0] = *reinterpret_cast<const uint4*>(&u[0]);
    dst[1] = *reinterpret_cast<const uint4*>(&u[8]);
}

// ---------------- kernel 1: fused conv; pinned-T14 register staging, dbuf LDS ------------
// 256 thr = 4 waves x 2 d-tiles. Staging thread (srow=tid>>1, sh=tid&1):
//   sh=0 -> Wv64 row bytes 0..63  (chunks 0-3, 4 loads)
//   sh=1 -> bytes 64..111 (w4,w5,w6) + TailT 32B; chunk6 = w6 | t0, chunk7 = t1 (5 loads)
__global__ __launch_bounds__(256, 2) void pcnn_conv_sent(
    const int* __restrict__ x,
    const ushort_t* __restrict__ Wv64, const ushort_t* __restrict__ TailT,
    const ushort_t* __restrict__ Bfrag, const float* __restrict__ bc,
    float* __restrict__ sent) {

    __shared__ __align__(16) unsigned char sembA[SENT_IMG];
    __shared__ __align__(16) unsigned char sembB[SENT_IMG];

    const int n0   = blockIdx.x * SPB;
    const int tid  = threadIdx.x;
    const int wv   = tid >> 6;
    const int lane = tid & 63;
    const int lhalf = lane >> 5;
    const int l31   = lane & 31;
    const int dcol0 = wv * 64 + l31;
    const int dcol1 = dcol0 + 32;

    const int srow = tid >> 1;
    const int sh   = tid & 1;
    const bool sact = (srow < LSEQ);

    // B fragments: this wave's two 32-wide d-tiles (L2-resident)
    bf16x8 Bf0[KSTEPS], Bf1[KSTEPS];
    #pragma unroll
    for (int ks = 0; ks < KSTEPS; ++ks) {
        int c = ks * 2 + lhalf;
        Bf0[ks] = *reinterpret_cast<const bf16x8*>(Bfrag + ((c * 256 + dcol0) << 3));
        Bf1[ks] = *reinterpret_cast<const bf16x8*>(Bfrag + ((c * 256 + dcol1) << 3));
    }
    const float bcv0 = (dcol0 < DFILT) ? bc[dcol0] : 0.0f;
    const float bcv1 = (dcol1 < DFILT) ? bc[dcol1] : 0.0f;

    // preload token ids for this block's sentences
    int tokv[SPB];
    #pragma unroll
    for (int s = 0; s < SPB; ++s)
        tokv[s] = sact ? x[(n0 + s) * LSEQ + srow] : 0;

    // zero pad rows 120..129 in all 8 chunks of BOTH buffers
    if (tid < 160) {
        int b = tid / 80, j = tid % 80;
        int c = j / 10, r = 120 + j % 10;
        unsigned char* base = (b == 0 ? sembA : sembB);
        *reinterpret_cast<uint4*>(base + c * CH_STRIDE + r * 16) = uint4{0, 0, 0, 0};
    }

    uint4 r0, r1, r2, r3, r4;
    // prologue: load + write sentence 0 into A
    if (sact) {
        const uint4* w = reinterpret_cast<const uint4*>(Wv64 + (size_t)tokv[0] * 64);
        if (sh == 0) { r0 = w[0]; r1 = w[1]; r2 = w[2]; r3 = w[3]; r4 = uint4{0,0,0,0}; }
        else {
            r0 = w[4]; r1 = w[5]; r2 = w[6];
            const uint4* t = reinterpret_cast<const uint4*>(TailT + (size_t)(n0 * LSEQ + srow) * 16);
            r3 = t[0]; r4 = t[1];
        }
        unsigned char* p = sembA + (sh * 4) * CH_STRIDE + srow * 16;
        if (sh == 0) {
            *reinterpret_cast<uint4*>(p)                 = r0;
            *reinterpret_cast<uint4*>(p + CH_STRIDE)     = r1;
            *reinterpret_cast<uint4*>(p + 2 * CH_STRIDE) = r2;
            *reinterpret_cast<uint4*>(p + 3 * CH_STRIDE) = r3;
        } else {
            uint4 m; m.x = r2.x | r3.x; m.y = r2.y | r3.y; m.z = r2.z | r3.z; m.w = r2.w | r3.w;
            *reinterpret_cast<uint4*>(p)                 = r0;
            *reinterpret_cast<uint4*>(p + CH_STRIDE)     = r1;
            *reinterpret_cast<uint4*>(p + 2 * CH_STRIDE) = m;
            *reinterpret_cast<uint4*>(p + 3 * CH_STRIDE) = r4;
        }
    }
    __syncthreads();

    #pragma unroll
    for (int s = 0; s < SPB; ++s) {
        unsigned char* cur = (s & 1) ? sembB : sembA;
        unsigned char* nxt = (s & 1) ? sembA : sembB;

        // T14: issue next sentence's loads; sched_barrier pins them BEFORE the MFMA block
        if (s + 1 < SPB && sact) {
            const uint4* w = reinterpret_cast<const uint4*>(Wv64 + (size_t)tokv[s + 1] * 64);
            if (sh == 0) { r0 = w[0]; r1 = w[1]; r2 = w[2]; r3 = w[3]; }
            else {
                r0 = w[4]; r1 = w[5]; r2 = w[6];
                const uint4* t = reinterpret_cast<const uint4*>(
                    TailT + (size_t)((n0 + s + 1) * LSEQ + srow) * 16);
                r3 = t[0]; r4 = t[1];
            }
        }
        __builtin_amdgcn_sched_barrier(0);   // loads must issue before compute

        float dmax0 = -1e30f, dmax1 = -1e30f;
        #pragma unroll
        for (int tt = 0; tt < 4; ++tt) {
            f32x16 a0, a1;
            #pragma unroll
            for (int r = 0; r < 16; ++r) { a0[r] = 0.0f; a1[r] = 0.0f; }
            int trow = tt * 32 + l31;
            #pragma unroll
            for (int ks = 0; ks < KSTEPS; ++ks) {
                int dh = ks >> 2, q = ks & 3;
                int chunk = q * 2 + lhalf;
                int l = trow + dh;
                bf16x8 Af = *reinterpret_cast<const bf16x8*>(cur + chunk * CH_STRIDE + l * 16);
                a0 = __builtin_amdgcn_mfma_f32_32x32x16_bf16(Af, Bf0[ks], a0, 0, 0, 0);
                a1 = __builtin_amdgcn_mfma_f32_32x32x16_bf16(Af, Bf1[ks], a1, 0, 0, 0);
            }
            #pragma unroll
            for (int r = 0; r < 16; ++r) {
                int t = tt * 32 + (r & 3) + 8 * (r >> 2) + 4 * lhalf;
                bool valid = (tt < 3) || (t < LSEQ - 2);
                if (valid) { dmax0 = fmaxf(dmax0, a0[r]); dmax1 = fmaxf(dmax1, a1[r]); }
            }
        }
        dmax0 = fmaxf(dmax0, __shfl_xor(dmax0, 32));
        dmax1 = fmaxf(dmax1, __shfl_xor(dmax1, 32));
        if (lhalf == 0) {
            int n = n0 + s;
            if (dcol0 < DFILT) sent[n * DFILT + dcol0] = tanhf(dmax0 + bcv0);
            if (dcol1 < DFILT) sent[n * DFILT + dcol1] = tanhf(dmax1 + bcv1);
        }

        // write staged regs into the OTHER buffer (safe: cur != nxt; nxt's readers done at s-1 barrier)
        if (s + 1 < SPB && sact) {
            unsigned char* p = nxt + (sh * 4) * CH_STRIDE + srow * 16;
            if (sh == 0) {
                *reinterpret_cast<uint4*>(p)                 = r0;
                *reinterpret_cast<uint4*>(p + CH_STRIDE)     = r1;
                *reinterpret_cast<uint4*>(p + 2 * CH_STRIDE) = r2;
                *reinterpret_cast<uint4*>(p + 3 * CH_STRIDE) = r3;
            } else {
                uint4 m; m.x = r2.x | r3.x; m.y = r2.y | r3.y; m.z = r2.z | r3.z; m.w = r2.w | r3.w;
                *reinterpret_cast<uint4*>(p)                 = r0;
                *reinterpret_cast<uint4*>(p + CH_STRIDE)     = r1;
                *reinterpret_cast<uint4*>(p + 2 * CH_STRIDE) = m;
                *reinterpret_cast<uint4*>(p + 3 * CH_STRIDE) = r4;
            }
        }
        __syncthreads();
    }
}

// ---------------- kernel 2: per-bag attention + scores + diag softmax ----------------
#define MAXNS 32
#define CPAD 56
__global__ __launch_bounds__(256) void pcnn_bag(
    const float* __restrict__ sent, const float* __restrict__ Wr, const float* __restrict__ br,
    const int* __restrict__ tshape, float* __restrict__ out) {

    __shared__ float s_sent[MAXNS * DFILT];
    __shared__ float s_Wr[NCLS * DFILT];
    __shared__ float s_e[MAXNS * CPAD];
    __shared__ float s_alpha[MAXNS * CPAD];
    __shared__ float s_sc[NCLS * NCLS];
    __shared__ float s_br[CPAD];

    const int g = blockIdx.x;
    const int tid = threadIdx.x;
    int start = tshape[g], end = tshape[g + 1];
    int ns = end - start;
    if (ns > MAXNS) ns = MAXNS;

    {
        int n2 = ns * (DFILT / 2);
        const float2* src = reinterpret_cast<const float2*>(sent + start * DFILT);
        for (int idx = tid; idx < n2; idx += 256)
            reinterpret_cast<float2*>(s_sent)[idx] = src[idx];
        const float2* wsrc = reinterpret_cast<const float2*>(Wr);
        for (int idx = tid; idx < (NCLS * DFILT) / 2; idx += 256)
            reinterpret_cast<float2*>(s_Wr)[idx] = wsrc[idx];
        if (tid < NCLS) s_br[tid] = br[tid];
    }
    __syncthreads();

    if (tid < 224) {
        int i0 = tid / 14, c0 = tid % 14;
        float a00 = 0, a01 = 0, a02 = 0, a03 = 0;
        float a10 = 0, a11 = 0, a12 = 0, a13 = 0;
        const float* s0p = s_sent + (2 * i0) * DFILT;
        const float* s1p = s_sent + (2 * i0 + 1) * DFILT;
        const float* w0p = s_Wr + (4 * c0 + 0) * DFILT;
        const float* w1p = s_Wr + (4 * c0 + 1) * DFILT;
        const float* w2p = (4 * c0 + 2 < NCLS) ? s_Wr + (4 * c0 + 2) * DFILT : s_Wr;
        const float* w3p = (4 * c0 + 3 < NCLS) ? s_Wr + (4 * c0 + 3) * DFILT : s_Wr;
        for (int d = 0; d < DFILT; ++d) {
            float s0 = s0p[d], s1 = s1p[d];
            float w0 = w0p[d], w1 = w1p[d], w2 = w2p[d], w3 = w3p[d];
            a00 = fmaf(s0, w0, a00); a01 = fmaf(s0, w1, a01);
            a02 = fmaf(s0, w2, a02); a03 = fmaf(s0, w3, a03);
            a10 = fmaf(s1, w0, a10); a11 = fmaf(s1, w1, a11);
            a12 = fmaf(s1, w2, a12); a13 = fmaf(s1, w3, a13);
        }
        float av[2][4] = {{a00, a01, a02, a03}, {a10, a11, a12, a13}};
        #pragma unroll
        for (int ii = 0; ii < 2; ++ii) {
            int i = 2 * i0 + ii;
            #pragma unroll
            for (int jj = 0; jj < 4; ++jj) {
                int c = 4 * c0 + jj;
                if (i < ns && c < NCLS) s_e[i * CPAD + c] = av[ii][jj] + s_br[c];
            }
        }
    }
    __syncthreads();

    if (tid < NCLS) {
        int c = tid;
        float m = -1e30f;
        for (int i = 0; i < ns; ++i) m = fmaxf(m, s_e[i * CPAD + c]);
        float den = 0.0f;
        for (int i = 0; i < ns; ++i) {
            float ex = expf(s_e[i * CPAD + c] - m);
            s_alpha[i * CPAD + c] = ex;
            den += ex;
        }
        float inv = 1.0f / den;
        for (int i = 0; i < ns; ++i) s_alpha[i * CPAD + c] *= inv;
    }
    __syncthreads();

    for (int task = tid; task < NCLS * 14; task += 256) {
        int c = task / 14, k0 = (task % 14) * 4;
        float b0 = s_br[k0], b1 = (k0+1<NCLS)?s_br[k0+1]:0.f, b2 = (k0+2<NCLS)?s_br[k0+2]:0.f, b3 = (k0+3<NCLS)?s_br[k0+3]:0.f;
        float a0 = 0, a1 = 0, a2 = 0, a3 = 0;
        for (int i = 0; i < ns; ++i) {
            float al = s_alpha[i * CPAD + c];
            const float* ep = s_e + i * CPAD + k0;
            a0 = fmaf(al, ep[0] - b0, a0);
            a1 = fmaf(al, (k0+1<NCLS?ep[1]:0.f) - b1, a1);
            a2 = fmaf(al, (k0+2<NCLS?ep[2]:0.f) - b2, a2);
            a3 = fmaf(al, (k0+3<NCLS?ep[3]:0.f) - b3, a3);
        }
        if (k0 + 0 < NCLS) s_sc[c * NCLS + k0 + 0] = a0 + b0;
        if (k0 + 1 < NCLS) s_sc[c * NCLS + k0 + 1] = a1 + b1;
        if (k0 + 2 < NCLS) s_sc[c * NCLS + k0 + 2] = a2 + b2;
        if (k0 + 3 < NCLS) s_sc[c * NCLS + k0 + 3] = a3 + b3;
    }
    __syncthreads();

    if (tid < NCLS) {
        int c = tid;
        float m = -1e30f;
        for (int k = 0; k < NCLS; ++k) m = fmaxf(m, s_sc[c * NCLS + k]);
        float den = 0.0f;
        for (int k = 0; k < NCLS; ++k) den += expf(s_sc[c * NCLS + k] - m);
        out[g * NCLS + c] = expf(s_sc[c * NCLS + c] - m) / den;
    }
}

extern "C" void kernel_launch(void* const* d_in, const int* in_sizes, int n_in,
                              void* d_out, int out_size, void* d_ws, size_t ws_size,
                              hipStream_t stream) {
    const int*   x   = (const int*)d_in[0];
    const int*   ldi = (const int*)d_in[1];
    const int*   rdi = (const int*)d_in[2];
    const int*   ts  = (const int*)d_in[3];
    const float* Wv  = (const float*)d_in[4];
    const float* pf1 = (const float*)d_in[5];
    const float* pf2 = (const float*)d_in[6];
    const float* Wc  = (const float*)d_in[7];
    const float* bc  = (const float*)d_in[8];
    const float* Wr  = (const float*)d_in[9];
    const float* br  = (const float*)d_in[10];
    float* out = (float*)d_out;

    char* ws = (char*)d_ws;
    ushort_t* Bfrag = (ushort_t*)(ws + OFF_BFRAG);
    ushort_t* Wv64  = (ushort_t*)(ws + OFF_WV64);
    ushort_t* pf1b  = (ushort_t*)(ws + OFF_PF1B);
    ushort_t* pf2b  = (ushort_t*)(ws + OFF_PF2B);
    float*    sent  = (float*)(ws + OFF_SENT);
    ushort_t* TailT = (ushort_t*)(ws + OFF_TAIL);

    pcnn_prep_b<<<(BFRAG_ELEMS + 255) / 256, 256, 0, stream>>>(Wc, pf1, pf2, Bfrag, pf1b, pf2b);
    pcnn_prep_wv<<<(80000 * 64) / 256, 256, 0, stream>>>(Wv, Wv64);
    pcnn_prep_tail<<<(NSENT * LSEQ + 255) / 256, 256, 0, stream>>>(ldi, rdi, pf1b, pf2b, TailT);
    pcnn_conv_sent<<<NSENT / SPB, 256, 0, stream>>>(x, Wv64, TailT, Bfrag, bc, sent);
    pcnn_bag<<<GBAGS, 256, 0, stream>>>(sent, Wr, br, ts, out);
}